// Round 3
// baseline (401.680 us; speedup 1.0000x reference)
//
#include <hip/hip_runtime.h>

// CTC forward loss, MI355X.
// Pass 1 (k_gather): per (t,b) log-softmax + gather of blank+100 label classes,
//   stored PRE-EXPONENTIATED as q = exp(lp - gmax) plus gmax (ln units).
//   Record layout (REC=104 floats): [0]=q_blank [1]=gmax [2..101]=q_lab[0..99] [102..103]=0
// Pass 2 (k_alpha): one wave per batch element, 4 states/lane, prob-space recursion
//   in F64 (dynamic range: intra-wave alpha spread reaches ~450 nats > f32 window)
//   with trigger-only power-of-2 rescaling (no wave reduction on the critical path).
// Pass 3 (k_final): deterministic wave sum of per-b log-likelihoods.

#define TT 2000
#define BB 64
#define VV 128
#define LL 100
#define REC 104
#define REC_BASE 256   // float offset of records in ws; ws[0..63] holds ll[b]
#define NEGF (-1e30f)
#define L2E 1.44269504f
#define LN2 0.69314718f
#define LN2D 0.6931471805599453

__device__ __forceinline__ float wave_max64(float v) {
#pragma unroll
  for (int o = 32; o > 0; o >>= 1) v = fmaxf(v, __shfl_xor(v, o, 64));
  return v;
}
__device__ __forceinline__ float wave_sum64(float v) {
#pragma unroll
  for (int o = 32; o > 0; o >>= 1) v += __shfl_xor(v, o, 64);
  return v;
}

__global__ __launch_bounds__(256) void k_gather(const float* __restrict__ acts,
                                                const int* __restrict__ target,
                                                float* __restrict__ ws) {
  const int lane = threadIdx.x & 63;
  const int w = threadIdx.x >> 6;
  const int r = blockIdx.x * 4 + w;          // record id = t*BB + b
  if (r >= TT * BB) return;
  const int b = r % BB;
  const float* row = acts + (size_t)r * VV;
  float x0 = row[lane];
  float x1 = row[lane + 64];
  // log-sum-exp over 128 logits (ln units)
  float m = wave_max64(fmaxf(x0, x1));
  float e = __builtin_exp2f((x0 - m) * L2E) + __builtin_exp2f((x1 - m) * L2E);
  float s = wave_sum64(e);
  float lse = m + __builtin_log2f(s) * LN2;
  // gather label classes: lane handles j=lane and j=64+lane
  const int* lab = target + b * LL;
  int c1 = lab[lane];                        // j = lane, always < 100
  int j2 = 64 + lane;
  int c2 = (j2 < LL) ? lab[j2] : 1;
  float y1lo = __shfl(x0, c1 & 63, 64);
  float y1hi = __shfl(x1, c1 & 63, 64);
  float y1 = (c1 < 64) ? y1lo : y1hi;
  float y2lo = __shfl(x0, c2 & 63, 64);
  float y2hi = __shfl(x1, c2 & 63, 64);
  float y2 = (c2 < 64) ? y2lo : y2hi;
  float g1 = y1 - lse;
  float g2 = (j2 < LL) ? (y2 - lse) : NEGF;
  float gb = __shfl(x0, 0, 64) - lse;        // blank = class 0
  float gm = wave_max64(fmaxf(fmaxf(g1, g2), gb));
  float q1 = __builtin_exp2f((g1 - gm) * L2E);
  float q2 = (j2 < LL) ? __builtin_exp2f((g2 - gm) * L2E) : 0.0f;
  float* rec = ws + REC_BASE + (size_t)r * REC;
  rec[2 + lane] = q1;                        // indices 2..65  (j=0..63)
  if (lane < 38) rec[66 + lane] = q2;        // indices 66..103 (j=64..101; j>=100 -> 0)
  if (lane == 0) { rec[0] = __builtin_exp2f((gb - gm) * L2E); rec[1] = gm; }
}

struct Rec2 { float2 h; float2 q; };

__device__ __forceinline__ void ld(const float* __restrict__ recs, int t, int b, int lidx, Rec2& r) {
  const float* p = recs + ((size_t)t * BB + b) * REC;
  r.h = *reinterpret_cast<const float2*>(p);              // {q_blank, gmax}
  r.q = *reinterpret_cast<const float2*>(p + 2 + 2 * lidx); // {q_lab[2l], q_lab[2l+1]}
}

__device__ __forceinline__ void step(const Rec2& r, int lane, double csm1, double csm3,
                                     double& a0, double& a1, double& a2, double& a3,
                                     double& msum, int& offs) {
  double p3 = __shfl_up(a3, 1, 64);          // full f64: f32-cast would re-flush corridor
  p3 = (lane == 0) ? 0.0 : p3;               // alpha[-1] = 0
  double qb = (double)r.h.x;
  // states 4l (blank), 4l+1 (lab 2l), 4l+2 (blank), 4l+3 (lab 2l+1)
  double n0 = (a0 + p3) * qb;
  double n1 = __builtin_fma(csm1, p3, a0 + a1) * (double)r.q.x;
  double n2 = (a1 + a2) * qb;
  double n3 = __builtin_fma(csm3, a1, a2 + a3) * (double)r.q.y;
  msum += (double)r.h.y;
  double lm = fmax(fmax(n0, n1), fmax(n2, n3));
  if (__all(lm < 0x1p-30)) {                 // wave max < 2^-30: scale up
    n0 *= 0x1p30; n1 *= 0x1p30; n2 *= 0x1p30; n3 *= 0x1p30;
    offs -= 30;
  } else if (__any(lm > 0x1p30)) {           // some lane > 2^30: scale down
    n0 *= 0x1p-30; n1 *= 0x1p-30; n2 *= 0x1p-30; n3 *= 0x1p-30;
    offs += 30;
  }
  a0 = n0; a1 = n1; a2 = n2; a3 = n3;
}

#define UNR 8

__global__ __launch_bounds__(64) void k_alpha(const int* __restrict__ target,
                                              const int* __restrict__ sizes,
                                              const int* __restrict__ lablens,
                                              float* __restrict__ ws) {
  const int b = blockIdx.x;
  const int lane = threadIdx.x;
  const int size = sizes[b];
  const float* recs = ws + REC_BASE;
  const int lidx = (lane < 50) ? lane : 50;  // lanes >=50 read the zero pads
  // per-lane skip masks: can_skip[4l+1] = lab[2l]!=lab[2l-1]; can_skip[4l+3] = lab[2l+1]!=lab[2l]
  const int* lab = target + b * LL;
  int i0 = 2 * lane, i1 = 2 * lane + 1;
  int l2 = (i0 < LL) ? lab[i0] : -1;
  int l2p1 = (i1 < LL) ? lab[i1] : -1;
  int lprev = __shfl_up(l2p1, 1, 64);
  double csm1 = (lane == 0 || l2 != lprev) ? 1.0 : 0.0;
  double csm3 = (l2p1 != l2) ? 1.0 : 0.0;
  // t=0 init: alpha[0]=lp_blank, alpha[1]=lp_lab0 (scaled space: q values, msum=gmax0)
  double a0 = 0., a1 = 0., a2 = 0., a3 = 0.;
  double msum;
  {
    const float* p = recs + (size_t)b * REC;
    msum = (double)p[1];
    if (lane == 0) { a0 = (double)p[0]; a1 = (double)p[2]; }
  }
  int offs = 0;
  Rec2 bufA[UNR], bufB[UNR];
  const int nfull = (size - 1) / UNR;
  if (nfull > 0) {
#pragma unroll
    for (int u = 0; u < UNR; ++u) ld(recs, 1 + u, b, lidx, bufA[u]);
  }
  for (int c = 0; c < nfull; ++c) {
    const int tn = 1 + (c + 1) * UNR;
    if ((c & 1) == 0) {
      if (c + 1 < nfull) {
#pragma unroll
        for (int u = 0; u < UNR; ++u) ld(recs, tn + u, b, lidx, bufB[u]);
      }
#pragma unroll
      for (int u = 0; u < UNR; ++u) step(bufA[u], lane, csm1, csm3, a0, a1, a2, a3, msum, offs);
    } else {
      if (c + 1 < nfull) {
#pragma unroll
        for (int u = 0; u < UNR; ++u) ld(recs, tn + u, b, lidx, bufA[u]);
      }
#pragma unroll
      for (int u = 0; u < UNR; ++u) step(bufB[u], lane, csm1, csm3, a0, a1, a2, a3, msum, offs);
    }
  }
  for (int t = 1 + nfull * UNR; t < size; ++t) {
    Rec2 r; ld(recs, t, b, lidx, r);
    step(r, lane, csm1, csm3, a0, a1, a2, a3, msum, offs);
  }
  // readout: ll = msum + ln2*offs + ln(A[2L-1] + A[2L])
  int Lb = lablens[b];
  int shi = 2 * Lb, slo = 2 * Lb - 1;
  double vhi, vlo;
  {
    int sl = shi >> 2, k = shi & 3;
    double v0 = __shfl(a0, sl, 64), v1 = __shfl(a1, sl, 64);
    double v2 = __shfl(a2, sl, 64), v3 = __shfl(a3, sl, 64);
    vhi = (k == 0) ? v0 : (k == 1) ? v1 : (k == 2) ? v2 : v3;
    sl = slo >> 2; k = slo & 3;
    v0 = __shfl(a0, sl, 64); v1 = __shfl(a1, sl, 64);
    v2 = __shfl(a2, sl, 64); v3 = __shfl(a3, sl, 64);
    vlo = (k == 0) ? v0 : (k == 1) ? v1 : (k == 2) ? v2 : v3;
  }
  if (lane == 0) {
    double s = vhi + vlo;
    long long bits = __double_as_longlong(s);
    int e = (int)((bits >> 52) & 0x7ffLL) - 1023;
    double mant = __longlong_as_double((bits & 0xFFFFFFFFFFFFFLL) | 0x3FF0000000000000LL);
    double lnm = (double)(__builtin_log2f((float)mant) * LN2);
    ws[b] = (float)(msum + LN2D * (double)offs + LN2D * (double)e + lnm);
  }
}

__global__ __launch_bounds__(64) void k_final(const float* __restrict__ ws, float* __restrict__ out) {
  float v = (threadIdx.x < BB) ? ws[threadIdx.x] : 0.0f;
  v = wave_sum64(v);
  if (threadIdx.x == 0) out[0] = -v;
}

extern "C" void kernel_launch(void* const* d_in, const int* in_sizes, int n_in,
                              void* d_out, int out_size, void* d_ws, size_t ws_size,
                              hipStream_t stream) {
  const float* acts   = (const float*)d_in[0];   // (T,B,V) f32
  const int* target   = (const int*)d_in[1];     // (B*L,) i32
  const int* sizes    = (const int*)d_in[2];     // (B,) i32
  const int* lablens  = (const int*)d_in[3];     // (B,) i32
  float* ws  = (float*)d_ws;                     // needs ~53.3 MB
  float* out = (float*)d_out;
  const int nrec = TT * BB;
  k_gather<<<dim3(nrec / 4), dim3(256), 0, stream>>>(acts, target, ws);
  k_alpha<<<dim3(BB), dim3(64), 0, stream>>>(target, sizes, lablens, ws);
  k_final<<<dim3(1), dim3(64), 0, stream>>>(ws, out);
}

// Round 5
// 259.058 us; speedup vs baseline: 1.5505x; 1.5505x over previous
//
#include <hip/hip_runtime.h>

// CTC forward loss, MI355X.
// Pass 1 (k_gather): per (t,b) log-softmax + gather, PRE-EXPONENTIATED:
//   q = exp(lp - gmax), record (104 f32): [0]=q_blank [1]=gmax [2+j]=q_lab[j] (j=0..99) [102..103]=0
//   Layout transposed: record(b,t) at ws + REC_BASE + (b*TT + t)*REC  (per-wave streaming in k_alpha).
// Pass 2 (k_alpha): one wave per b. 4 own states + 7 halo states per lane; one 9-bpermute
//   exchange per 4 steps (frontier advances 2 states/step -> 10/8/6/4 update pyramid).
//   f32 prob-space with PER-LANE octave counter (offs), reconciled at exchanges. No votes.
//   offs inheritance is LEFT-ONLY (lanes 0/1 masked: no ring-wrap; mass flows left->right).
// Pass 3 (k_final): deterministic wave sum.

#define TT 2000
#define BB 64
#define VV 128
#define LL 100
#define REC 104
#define REC_BASE 256
#define NEGF (-1e30f)
#define L2E 1.44269504f
#define LN2 0.69314718f

__device__ __forceinline__ float wave_max64(float v) {
#pragma unroll
  for (int o = 32; o > 0; o >>= 1) v = fmaxf(v, __shfl_xor(v, o, 64));
  return v;
}
__device__ __forceinline__ float wave_sum64(float v) {
#pragma unroll
  for (int o = 32; o > 0; o >>= 1) v += __shfl_xor(v, o, 64);
  return v;
}

__global__ __launch_bounds__(256) void k_gather(const float* __restrict__ acts,
                                                const int* __restrict__ target,
                                                float* __restrict__ ws) {
  const int lane = threadIdx.x & 63;
  const int w = threadIdx.x >> 6;
  const int r = blockIdx.x * 4 + w;          // r = t*BB + b
  if (r >= TT * BB) return;
  const int b = r % BB;
  const int t = r / BB;
  const float* row = acts + (size_t)r * VV;
  float x0 = row[lane];
  float x1 = row[lane + 64];
  float m = wave_max64(fmaxf(x0, x1));
  float e = __builtin_exp2f((x0 - m) * L2E) + __builtin_exp2f((x1 - m) * L2E);
  float s = wave_sum64(e);
  float lse = m + __builtin_log2f(s) * LN2;
  const int* lab = target + b * LL;
  int c1 = lab[lane];
  int j2 = 64 + lane;
  int c2 = (j2 < LL) ? lab[j2] : 1;
  float y1lo = __shfl(x0, c1 & 63, 64);
  float y1hi = __shfl(x1, c1 & 63, 64);
  float y1 = (c1 < 64) ? y1lo : y1hi;
  float y2lo = __shfl(x0, c2 & 63, 64);
  float y2hi = __shfl(x1, c2 & 63, 64);
  float y2 = (c2 < 64) ? y2lo : y2hi;
  float g1 = y1 - lse;
  float g2 = (j2 < LL) ? (y2 - lse) : NEGF;
  float gb = __shfl(x0, 0, 64) - lse;
  float gm = wave_max64(fmaxf(fmaxf(g1, g2), gb));
  float q1 = __builtin_exp2f((g1 - gm) * L2E);
  float q2 = (j2 < LL) ? __builtin_exp2f((g2 - gm) * L2E) : 0.0f;
  float* rec = ws + REC_BASE + ((size_t)b * TT + t) * REC;
  rec[2 + lane] = q1;
  if (lane < 38) rec[66 + lane] = q2;
  if (lane == 0) { rec[0] = __builtin_exp2f((gb - gm) * L2E); rec[1] = gm; }
}

struct Blk {
  float2 h0, h1, h2, h3;   // (q_blank, gmax) per step
  float2 c0, c1, c2, c3;   // labels (2l, 2l+1)
  float2 b0, b1, b2;       // labels (2l-2, 2l-1) steps 0..2
  float2 a0;               // labels (2l-4, 2l-3) step 0
};

#define ISSUE(K, cidx) do {                                                  \
  int bi_ = (cidx); bi_ = (bi_ < 498) ? bi_ : 498;                           \
  const float* r0_ = recs_b + (size_t)(1 + 4 * bi_) * REC;                   \
  K.h0 = *(const float2*)(r0_);           K.c0 = *(const float2*)(r0_ + ofC);\
  K.b0 = *(const float2*)(r0_ + ofB);     K.a0 = *(const float2*)(r0_ + ofA);\
  K.h1 = *(const float2*)(r0_ + REC);     K.c1 = *(const float2*)(r0_ + REC + ofC);\
  K.b1 = *(const float2*)(r0_ + REC + ofB);                                  \
  K.h2 = *(const float2*)(r0_ + 2*REC);   K.c2 = *(const float2*)(r0_ + 2*REC + ofC);\
  K.b2 = *(const float2*)(r0_ + 2*REC + ofB);                                \
  K.h3 = *(const float2*)(r0_ + 3*REC);   K.c3 = *(const float2*)(r0_ + 3*REC + ofC);\
} while (0)

// top-down in-place update; NH = number of halo pairs updated (3/2/1/0)
#define STEP(hh, qc, qbx, qax, NH) do {                                      \
  const float qb_ = hh.x; msum += hh.y;                                      \
  o3 = __builtin_fmaf(cs_o3, o1, o3 + o2) * qc.y;                            \
  o2 = (o2 + o1) * qb_;                                                      \
  o1 = __builtin_fmaf(cs_o1, h1, o1 + o0) * qc.x;                            \
  o0 = (o0 + h1) * qb_;                                                      \
  if (NH >= 1) { h1 = __builtin_fmaf(cs_h1, h3, h1 + h2) * qbx.y;            \
                 h2 = (h2 + h3) * qb_; }                                     \
  if (NH >= 2) { h3 = __builtin_fmaf(cs_h3, h5, h3 + h4) * qbx.x;            \
                 h4 = (h4 + h5) * qb_; }                                     \
  if (NH >= 3) { h5 = __builtin_fmaf(cs_h5, h7, h5 + h6) * qax.y;            \
                 h6 = (h6 + h7) * qb_; }                                     \
} while (0)

#define EPILOGUE() do {                                                      \
  int s3_ = __builtin_amdgcn_ds_bpermute(idx1, __float_as_int(o3));          \
  int s2_ = __builtin_amdgcn_ds_bpermute(idx1, __float_as_int(o2));          \
  int s1_ = __builtin_amdgcn_ds_bpermute(idx1, __float_as_int(o1));          \
  int s0_ = __builtin_amdgcn_ds_bpermute(idx1, __float_as_int(o0));          \
  int u3_ = __builtin_amdgcn_ds_bpermute(idx2, __float_as_int(o3));          \
  int u2_ = __builtin_amdgcn_ds_bpermute(idx2, __float_as_int(o2));          \
  int u1_ = __builtin_amdgcn_ds_bpermute(idx2, __float_as_int(o1));          \
  int ro1_ = __builtin_amdgcn_ds_bpermute(idx1, offs);                       \
  int ro2_ = __builtin_amdgcn_ds_bpermute(idx2, offs);                       \
  ro1_ = (l >= 1) ? ro1_ : -(1 << 29);   /* no ring-wrap: left-only */       \
  ro2_ = (l >= 2) ? ro2_ : -(1 << 29);                                       \
  float m_ = fmaxf(fmaxf(o0, o1), fmaxf(o2, o3));                            \
  int eb_ = (int)((__float_as_uint(m_) >> 23) & 255u);                       \
  int t1_ = offs + (eb_ ? (eb_ - 127) : -126);  /* bounded self-renorm */    \
  int mx_ = (ro1_ > ro2_) ? ro1_ : ro2_;                                     \
  int onew_ = (t1_ > mx_) ? t1_ : mx_;                                       \
  int ds_ = offs - onew_;                                                    \
  ds_ = (ds_ < -300) ? -300 : ds_;                                           \
  int d1_ = ro1_ - onew_, d2_ = ro2_ - onew_;                                \
  d1_ = (d1_ < -300) ? -300 : d1_;                                           \
  d2_ = (d2_ < -300) ? -300 : d2_;                                           \
  o0 = ldexpf(o0, ds_); o1 = ldexpf(o1, ds_);                                \
  o2 = ldexpf(o2, ds_); o3 = ldexpf(o3, ds_);                                \
  h1 = ldexpf(__int_as_float(s3_), d1_) * msk1;                              \
  h2 = ldexpf(__int_as_float(s2_), d1_) * msk2;                              \
  h3 = ldexpf(__int_as_float(s1_), d1_) * msk3;                              \
  h4 = ldexpf(__int_as_float(s0_), d1_) * msk4;                              \
  h5 = ldexpf(__int_as_float(u3_), d2_) * msk5;                              \
  h6 = ldexpf(__int_as_float(u2_), d2_) * msk6;                              \
  h7 = ldexpf(__int_as_float(u1_), d2_) * msk7;                              \
  offs = onew_;                                                              \
} while (0)

#define COMP(K) do {                                                         \
  STEP(K.h0, K.c0, K.b0, K.a0, 3);                                           \
  STEP(K.h1, K.c1, K.b1, K.a0, 2);                                           \
  STEP(K.h2, K.c2, K.b2, K.a0, 1);                                           \
  STEP(K.h3, K.c3, K.b2, K.a0, 0);                                           \
  EPILOGUE();                                                                \
} while (0)

__global__ __launch_bounds__(64) void k_alpha(const int* __restrict__ target,
                                              const int* __restrict__ sizes,
                                              const int* __restrict__ lablens,
                                              float* __restrict__ ws) {
  const int b = blockIdx.x;
  const int l = threadIdx.x;
  const int size = sizes[b];
  const float* recs_b = ws + REC_BASE + (size_t)b * TT * REC;
  const int lc = (l < 50) ? l : 50;
  const int ofC = 2 + 2 * lc;
  const int ofB = (ofC >= 4) ? (ofC - 2) : 2;
  const int ofA = (ofC >= 6) ? (ofC - 4) : 2;
  const int idx1 = ((l + 63) & 63) << 2;
  const int idx2 = ((l + 62) & 63) << 2;
  // skip coefficients (labels j = 2l-4 .. 2l+1, clamped loads; OOB masked by q=0/halo=0)
  const int* lab = target + b * LL;
  int jj;
  jj = 2 * l + 1; jj = jj < 0 ? 0 : (jj > 99 ? 99 : jj); int L5 = lab[jj];
  jj = 2 * l;     jj = jj < 0 ? 0 : (jj > 99 ? 99 : jj); int L4 = lab[jj];
  jj = 2 * l - 1; jj = jj < 0 ? 0 : (jj > 99 ? 99 : jj); int L3 = lab[jj];
  jj = 2 * l - 2; jj = jj < 0 ? 0 : (jj > 99 ? 99 : jj); int L2v = lab[jj];
  jj = 2 * l - 3; jj = jj < 0 ? 0 : (jj > 99 ? 99 : jj); int L1v = lab[jj];
  jj = 2 * l - 4; jj = jj < 0 ? 0 : (jj > 99 ? 99 : jj); int L0v = lab[jj];
  const float cs_o3 = (L5 != L4) ? 1.f : 0.f;
  const float cs_o1 = (L4 != L3) ? 1.f : 0.f;
  const float cs_h1 = (L3 != L2v) ? 1.f : 0.f;
  const float cs_h3 = (L2v != L1v) ? 1.f : 0.f;
  const float cs_h5 = (L1v != L0v) ? 1.f : 0.f;
  const float msk1 = (4 * l - 1 >= 0) ? 1.f : 0.f;
  const float msk2 = (4 * l - 2 >= 0) ? 1.f : 0.f;
  const float msk3 = (4 * l - 3 >= 0) ? 1.f : 0.f;
  const float msk4 = (4 * l - 4 >= 0) ? 1.f : 0.f;
  const float msk5 = (4 * l - 5 >= 0) ? 1.f : 0.f;
  const float msk6 = (4 * l - 6 >= 0) ? 1.f : 0.f;
  const float msk7 = (4 * l - 7 >= 0) ? 1.f : 0.f;
  // init at t=0: alpha0[0]=q_blank, alpha0[1]=q_lab0 (scaling: msum = gmax(t=0), offs=0)
  float o0 = 0.f, o1 = 0.f, o2 = 0.f, o3 = 0.f;
  float h1 = 0.f, h2 = 0.f, h3 = 0.f, h4 = 0.f, h5 = 0.f, h6 = 0.f, h7 = 0.f;
  int offs = 0;
  float msum = recs_b[1];
  if (l == 0) { o0 = recs_b[0]; o1 = recs_b[2]; }
  if (l == 1) { h3 = recs_b[2]; h4 = recs_b[0]; }   // halo copies of alpha0[1], alpha0[0]
  if (l == 2) { h7 = recs_b[2]; }                   // alpha0[1]

  const int nb = (size - 1) >> 2;
  Blk A, B, C;
  ISSUE(A, 0);
  ISSUE(B, 1);
  int c = 0;
  for (; c + 3 <= nb; c += 3) {
    ISSUE(C, c + 2); COMP(A);
    ISSUE(A, c + 3); COMP(B);
    ISSUE(B, c + 4); COMP(C);
  }
  if (nb - c >= 1) { COMP(A); }
  if (nb - c >= 2) { COMP(B); }
  // tail steps (<= 3)
  {
    int rno1 = __builtin_amdgcn_ds_bpermute(idx1, offs);
    int dtl = rno1 - offs;
    dtl = (dtl > 120) ? 120 : ((dtl < -300) ? -300 : dtl);
    for (int t = 1 + 4 * nb; t < size; ++t) {
      const float* rt = recs_b + (size_t)t * REC;
      float2 hh = *(const float2*)rt;
      float2 qc = *(const float2*)(rt + ofC);
      int rp = __builtin_amdgcn_ds_bpermute(idx1, __float_as_int(o3));
      float p = ldexpf(__int_as_float(rp), dtl) * msk1;
      msum += hh.y;
      o3 = __builtin_fmaf(cs_o3, o1, o3 + o2) * qc.y;
      o2 = (o2 + o1) * hh.x;
      o1 = __builtin_fmaf(cs_o1, p, o1 + o0) * qc.x;
      o0 = (o0 + p) * hh.x;
    }
  }
  // readout: states 2Lb (hi) and 2Lb-1 (lo)
  int Lb = lablens[b];
  int shi = 2 * Lb, slo = shi - 1;
  int kh = shi & 3, kl = slo & 3;
  float selhi = (kh == 0) ? o0 : (kh == 1) ? o1 : (kh == 2) ? o2 : o3;
  float sello = (kl == 0) ? o0 : (kl == 1) ? o1 : (kl == 2) ? o2 : o3;
  int vh_ = __builtin_amdgcn_ds_bpermute((shi >> 2) << 2, __float_as_int(selhi));
  int oh_ = __builtin_amdgcn_ds_bpermute((shi >> 2) << 2, offs);
  int vl_ = __builtin_amdgcn_ds_bpermute((slo >> 2) << 2, __float_as_int(sello));
  int ol_ = __builtin_amdgcn_ds_bpermute((slo >> 2) << 2, offs);
  if (l == 0) {
    float vhi = __int_as_float(vh_), vlo = __int_as_float(vl_);
    int dd = ol_ - oh_;
    float vb, vs; int ob;
    if (dd > 0) { vb = vlo; vs = vhi; ob = ol_; dd = -dd; }
    else        { vb = vhi; vs = vlo; ob = oh_; }
    dd = (dd < -300) ? -300 : dd;
    float v = vb + ldexpf(vs, dd);
    ws[b] = msum + LN2 * ((float)ob + __builtin_log2f(v));
  }
}

__global__ __launch_bounds__(64) void k_final(const float* __restrict__ ws, float* __restrict__ out) {
  float v = (threadIdx.x < BB) ? ws[threadIdx.x] : 0.0f;
  v = wave_sum64(v);
  if (threadIdx.x == 0) out[0] = -v;
}

extern "C" void kernel_launch(void* const* d_in, const int* in_sizes, int n_in,
                              void* d_out, int out_size, void* d_ws, size_t ws_size,
                              hipStream_t stream) {
  const float* acts  = (const float*)d_in[0];
  const int* target  = (const int*)d_in[1];
  const int* sizes   = (const int*)d_in[2];
  const int* lablens = (const int*)d_in[3];
  float* ws  = (float*)d_ws;
  float* out = (float*)d_out;
  const int nrec = TT * BB;
  k_gather<<<dim3(nrec / 4), dim3(256), 0, stream>>>(acts, target, ws);
  k_alpha<<<dim3(BB), dim3(64), 0, stream>>>(target, sizes, lablens, ws);
  k_final<<<dim3(1), dim3(64), 0, stream>>>(ws, out);
}